// Round 1
// baseline (1142.257 us; speedup 1.0000x reference)
//
#include <hip/hip_runtime.h>

#define NSITE 512
#define DD    64
#define NB    64
#define NO    10

// In-place per-site transpose of W_right: slab [l][r] (float2 over feature dim) -> [r][l].
// One block per site; each (l<r) pair swapped by exactly one thread -> no races.
__global__ __launch_bounds__(256) void wr_transpose_kernel(float2* __restrict__ wr) {
    const int s = blockIdx.x;
    float2* slab = wr + s * (DD * DD);
    for (int idx = threadIdx.x; idx < DD * DD; idx += 256) {
        const int l = idx >> 6;
        const int r = idx & 63;
        if (l < r) {
            const int tidx = r * DD + l;
            float2 a = slab[idx];
            float2 b = slab[tidx];
            slab[idx]  = b;
            slab[tidx] = a;
        }
    }
}

// One wave (64 lanes) per (side, batch) chain; lane = output component.
// Left  (side 0): v_new[r] = sum_l v[l] * (x0*W0[l,r] + x1*W1[l,r]),  s = 0..511
// Right (side 1): w_new[l] = sum_r (x0*N0[l,r] + x1*N1[l,r]) * w[r],  s = 511..0,
//                 reads the transposed slabs so the access pattern matches the left side.
// Single-wave block: LDS ops execute in wave program order -> no __syncthreads in the
// hot loop, so the W loads for site t+1 can stay in flight across the carried-v update.
__global__ __launch_bounds__(64) void scan_kernel(
        const float* __restrict__ x,
        const float* __restrict__ wl,
        const float* __restrict__ wrt,
        float* __restrict__ vout) {
    const int chain = blockIdx.x;     // 0..127
    const int side  = chain >> 6;     // 0: left fwd, 1: right bwd (transposed slabs)
    const int b     = chain & (NB - 1);
    const int lane  = threadIdx.x;

    __shared__ __align__(16) float vsh[DD];
    vsh[lane] = (lane == 0) ? 1.0f : 0.0f;   // open-boundary edge vector e

    const float2* __restrict__ W  = (const float2*)(side ? wrt : wl);
    const float2* __restrict__ xp = ((const float2*)x) + b * 1024 + (side ? NSITE : 0);

    for (int t = 0; t < NSITE; ++t) {
        const int s = side ? (NSITE - 1 - t) : t;
        const float2* __restrict__ slab = W + s * (DD * DD);
        const float2 xv = xp[s];
        float y0 = 0.f, y1 = 0.f;
        #pragma unroll
        for (int l4 = 0; l4 < DD / 4; ++l4) {
            const float4 vv = ((const float4*)vsh)[l4];   // broadcast ds_read_b128
            float2 w;
            w = slab[(l4 * 4 + 0) * DD + lane]; y0 += vv.x * w.x; y1 += vv.x * w.y;
            w = slab[(l4 * 4 + 1) * DD + lane]; y0 += vv.y * w.x; y1 += vv.y * w.y;
            w = slab[(l4 * 4 + 2) * DD + lane]; y0 += vv.z * w.x; y1 += vv.z * w.y;
            w = slab[(l4 * 4 + 3) * DD + lane]; y0 += vv.w * w.x; y1 += vv.w * w.y;
        }
        const float vnew = xv.x * y0 + xv.y * y1;
        vsh[lane] = vnew;   // same-array dependence keeps program order; wave-lockstep is safe
    }
    vout[chain * DD + lane] = vsh[lane];
}

// out[b,o] = sum_{l,r} vL[b,l] * core[o,l,r] * wR[b,r]
// lane = r: partial_r = wR[r] * sum_l vL[l]*core[o,l,r]; wave shuffle-reduce over r.
__global__ __launch_bounds__(64) void finalize_kernel(
        const float* __restrict__ core,
        const float* __restrict__ vbuf,
        float* __restrict__ out) {
    const int b    = blockIdx.x;
    const int lane = threadIdx.x;
    __shared__ float vls[DD];
    vls[lane] = vbuf[b * DD + lane];          // vL for this batch
    const float wr = vbuf[(NB + b) * DD + lane];  // wR[lane]
    __syncthreads();
    for (int o = 0; o < NO; ++o) {
        float acc = 0.f;
        #pragma unroll 8
        for (int l = 0; l < DD; ++l)
            acc += vls[l] * core[(o * DD + l) * DD + lane];   // lane-coalesced
        acc *= wr;
        #pragma unroll
        for (int off = 32; off > 0; off >>= 1)
            acc += __shfl_xor(acc, off, 64);
        if (lane == 0) out[b * NO + o] = acc;
    }
}

extern "C" void kernel_launch(void* const* d_in, const int* in_sizes, int n_in,
                              void* d_out, int out_size, void* d_ws, size_t ws_size,
                              hipStream_t stream) {
    const float* x    = (const float*)d_in[0];   // [64][1024][2] f32
    const float* wl   = (const float*)d_in[1];   // [512][64][64][2] f32
    const float* core = (const float*)d_in[2];   // [10][64][64] f32
    float*       wr   = (float*)d_in[3];         // [512][64][64][2] f32, transposed in place
                                                 // (harness restores pristine before every launch)
    float* vbuf = (float*)d_ws;                  // 128*64 floats = 32 KB scratch

    wr_transpose_kernel<<<NSITE, 256, 0, stream>>>((float2*)wr);
    scan_kernel<<<2 * NB, DD, 0, stream>>>(x, wl, wr, vbuf);
    finalize_kernel<<<NB, DD, 0, stream>>>(core, vbuf, (float*)d_out);
}

// Round 2
// 655.965 us; speedup vs baseline: 1.7413x; 1.7413x over previous
//
#include <hip/hip_runtime.h>
#include <stdint.h>

#define NSITE 512
#define DD    64
#define NB    64
#define NO    10
#define SLAB_DW (DD*DD*2)      // 8192 floats (32 KB) per original fp32 site slab
#define PACK_U2 (DD*DD/2)      // 2048 uint2 (16 KB) per packed bf16 site

// ---------------------------------------------------------------------------
// Pack W (fp32, [s][l][r][f]) -> bf16 cells IN PLACE into the front 16 KB of
// each 32 KB slab. Cell (p, r) 8B = { pack(W0[2p][r], W0[2p+1][r]),
//                                     pack(W1[2p][r], W1[2p+1][r]) }.
// Right-side slabs are transposed (W'[l][r] = W[r][l]) during the pack, so the
// scan kernel is identical for both directions. LDS-staged so the transposed
// gather stays cheap and in-place writes are race-free (write region is a
// subset of the read region, fully read into LDS before the barrier).
// ---------------------------------------------------------------------------
__global__ __launch_bounds__(256) void pack_kernel(float* __restrict__ wl,
                                                   float* __restrict__ wr) {
    const int g     = blockIdx.x;            // 0..1023
    const int right = (g >= NSITE) ? 1 : 0;
    const int s     = right ? g - NSITE : g;
    float* base = (right ? wr : wl) + (size_t)s * SLAB_DW;

    __shared__ float lds[SLAB_DW];           // 32 KB
    const float4* src4 = (const float4*)base;
    float4*       lds4 = (float4*)lds;
    #pragma unroll
    for (int k = 0; k < 8; ++k)
        lds4[threadIdx.x + 256*k] = src4[threadIdx.x + 256*k];
    __syncthreads();

    uint2* out = (uint2*)base;               // front 16 KB of the slab
    #pragma unroll
    for (int k = 0; k < 8; ++k) {
        const int id = threadIdx.x + 256*k;  // 0..2047
        const int p  = id >> 6;
        const int r  = id & 63;
        const int l0 = 2*p, l1 = 2*p + 1;
        float a0, a1, b0, b1;
        if (!right) {
            a0 = lds[(l0*DD + r)*2 + 0]; a1 = lds[(l1*DD + r)*2 + 0];
            b0 = lds[(l0*DD + r)*2 + 1]; b1 = lds[(l1*DD + r)*2 + 1];
        } else {                              // transposed gather
            a0 = lds[(r*DD + l0)*2 + 0]; a1 = lds[(r*DD + l1)*2 + 0];
            b0 = lds[(r*DD + l0)*2 + 1]; b1 = lds[(r*DD + l1)*2 + 1];
        }
        uint2 cell;
        cell.x = (__float_as_uint(a0) >> 16) | (__float_as_uint(a1) & 0xFFFF0000u);
        cell.y = (__float_as_uint(b0) >> 16) | (__float_as_uint(b1) & 0xFFFF0000u);
        out[id] = cell;
    }
}

// ---------------------------------------------------------------------------
// Async 16B global->LDS (zero VGPR landing cost). LDS dest is wave-uniform
// base; HW scatters lane*16.
// ---------------------------------------------------------------------------
__device__ __forceinline__ void dma16(const void* gp, void* lp) {
    __builtin_amdgcn_global_load_lds(
        (const __attribute__((address_space(1))) uint32_t*)gp,
        (__attribute__((address_space(3))) uint32_t*)lp, 16, 0, 0);
}

// ---------------------------------------------------------------------------
// One wave per (side, batch) chain. Triple-buffered LDS, prefetch depth 2,
// manual s_waitcnt vmcnt(32) = 0x8F70 (vm hi2=2 in [15:14], lgkm=0xF, exp=7).
// No barriers anywhere in the hot loop (single-wave block -> LDS ops are
// program-ordered), so the DMA queue never drains.
// ---------------------------------------------------------------------------
__global__ __launch_bounds__(64) void scan_kernel(const float* __restrict__ x,
        const float* __restrict__ wl, const float* __restrict__ wr,
        float* __restrict__ vout) {
    const int chain = blockIdx.x;          // 0..127
    const int side  = chain >> 6;
    const int b     = chain & (NB - 1);
    const int lane  = threadIdx.x;

    __shared__ uint2  buf[3][PACK_U2];     // 48 KB W ring
    __shared__ float2 xsh[NSITE];          // 4 KB x in chain order
    __shared__ __align__(16) float vsh[DD];

    const char* wbase = (const char*)(side ? wr : wl);
    const float2* xp = ((const float2*)x) + b * 1024 + (side ? NSITE : 0);
    #pragma unroll
    for (int k = 0; k < 8; ++k) {
        const int t  = lane + 64*k;
        const int sl = side ? (NSITE - 1 - t) : t;
        xsh[t] = xp[sl];
    }
    vsh[lane] = (lane == 0) ? 1.0f : 0.0f;

    // site byte offset for chain step t (slabs are 32 KB apart, packed data in front 16 KB)
    auto site_off = [&](int t) -> size_t {
        const int sl = side ? (NSITE - 1 - t) : t;
        return (size_t)sl * (SLAB_DW * 4);
    };

    #pragma unroll
    for (int c = 0; c < 16; ++c)
        dma16(wbase + site_off(0) + c*1024 + lane*16, (void*)(buf[0] + c*128));
    #pragma unroll
    for (int c = 0; c < 16; ++c)
        dma16(wbase + site_off(1) + c*1024 + lane*16, (void*)(buf[1] + c*128));

    int slot = 0;
    for (int t = 0; t < NSITE; ++t) {
        int t2 = t + 2; if (t2 > NSITE - 1) t2 = NSITE - 1;   // clamped dummy prefetch
        const int slot2 = (slot >= 1) ? slot - 1 : slot + 2;  // (slot+2)%3, never == slot
        const char* sb = wbase + site_off(t2);
        #pragma unroll
        for (int c = 0; c < 16; ++c)
            dma16(sb + c*1024 + lane*16, (void*)(buf[slot2] + c*128));

        __builtin_amdgcn_s_waitcnt(0x8F70);   // vmcnt(32): current slot's 16 DMAs done

        const uint2* __restrict__ w = buf[slot];
        const float2 xv = xsh[t];
        float y0a = 0.f, y0b = 0.f, y1a = 0.f, y1b = 0.f;
        const float4* v4 = (const float4*)vsh;
        #pragma unroll
        for (int j = 0; j < 16; ++j) {
            const float4 vv = v4[j];          // broadcast ds_read_b128
            uint2 ua = w[(2*j + 0)*DD + lane];
            uint2 ub = w[(2*j + 1)*DD + lane];
            float w00 = __uint_as_float(ua.x << 16);
            float w01 = __uint_as_float(ua.x & 0xFFFF0000u);
            float w10 = __uint_as_float(ua.y << 16);
            float w11 = __uint_as_float(ua.y & 0xFFFF0000u);
            y0a = fmaf(vv.x, w00, y0a); y0a = fmaf(vv.y, w01, y0a);
            y1a = fmaf(vv.x, w10, y1a); y1a = fmaf(vv.y, w11, y1a);
            w00 = __uint_as_float(ub.x << 16);
            w01 = __uint_as_float(ub.x & 0xFFFF0000u);
            w10 = __uint_as_float(ub.y << 16);
            w11 = __uint_as_float(ub.y & 0xFFFF0000u);
            y0b = fmaf(vv.z, w00, y0b); y0b = fmaf(vv.w, w01, y0b);
            y1b = fmaf(vv.z, w10, y1b); y1b = fmaf(vv.w, w11, y1b);
        }
        const float vnew = xv.x * (y0a + y0b) + xv.y * (y1a + y1b);
        vsh[lane] = vnew;                     // program-ordered vs next site's v4 reads
        slot = (slot == 2) ? 0 : slot + 1;
    }
    vout[chain * DD + lane] = vsh[lane];
}

// out[b,o] = sum_{l,r} vL[b,l] * core[o,l,r] * wR[b,r]
__global__ __launch_bounds__(64) void finalize_kernel(
        const float* __restrict__ core,
        const float* __restrict__ vbuf,
        float* __restrict__ out) {
    const int b    = blockIdx.x;
    const int lane = threadIdx.x;
    __shared__ float vls[DD];
    vls[lane] = vbuf[b * DD + lane];               // vL
    const float wr = vbuf[(NB + b) * DD + lane];   // wR[lane]
    __syncthreads();
    for (int o = 0; o < NO; ++o) {
        float acc = 0.f;
        #pragma unroll 8
        for (int l = 0; l < DD; ++l)
            acc += vls[l] * core[(o * DD + l) * DD + lane];
        acc *= wr;
        #pragma unroll
        for (int off = 32; off > 0; off >>= 1)
            acc += __shfl_xor(acc, off, 64);
        if (lane == 0) out[b * NO + o] = acc;
    }
}

extern "C" void kernel_launch(void* const* d_in, const int* in_sizes, int n_in,
                              void* d_out, int out_size, void* d_ws, size_t ws_size,
                              hipStream_t stream) {
    const float* x    = (const float*)d_in[0];   // [64][1024][2]
    float*       wl   = (float*)d_in[1];         // [512][64][64][2], packed in place
    const float* core = (const float*)d_in[2];   // [10][64][64]
    float*       wr   = (float*)d_in[3];         // [512][64][64][2], packed+transposed in place
    float* vbuf = (float*)d_ws;                  // 32 KB scratch

    pack_kernel<<<2 * NSITE, 256, 0, stream>>>(wl, wr);
    scan_kernel<<<2 * NB, DD, 0, stream>>>(x, wl, wr, vbuf);
    finalize_kernel<<<NB, DD, 0, stream>>>(core, vbuf, (float*)d_out);
}

// Round 3
// 239.340 us; speedup vs baseline: 4.7725x; 2.7407x over previous
//
#include <hip/hip_runtime.h>
#include <hip/hip_bf16.h>
#include <stdint.h>

#define NSITE 512
#define DD    64
#define NB    64
#define NO    10
#define NSEG  8
#define SEGLEN 64
#define SLAB_BYTES 32768   // fp32 site slab stride (64*64*2*4B)
#define PACK_BYTES 16384   // packed bf16 A-layout slab (front half)

typedef short  bf16x8  __attribute__((ext_vector_type(8)));
typedef float  f32x16  __attribute__((ext_vector_type(16)));

// ---------------------------------------------------------------------------
// Pack W fp32 [s][l][r][w] -> bf16 A-operand layout, IN PLACE (front 16 KB of
// each 32 KB slab). Left slabs transposed (A[m][k] = W[k][m]); right direct.
// Layout (byte): w*8192 + m*128 + ((k>>3) ^ (m&7))*16 + (k&7)*2  — the XOR
// swizzle spreads the m*128 stride across all 32 LDS banks for frag reads.
// DMA to LDS is a verbatim copy, so stage1 reads with the same formula.
// ---------------------------------------------------------------------------
__global__ __launch_bounds__(256) void pack_kernel(float* __restrict__ wl,
                                                   float* __restrict__ wr) {
    const int g = blockIdx.x;                 // 0..1023
    const int right = (g >= NSITE) ? 1 : 0;
    const int s = right ? g - NSITE : g;
    float* base = (right ? wr : wl) + (size_t)s * (SLAB_BYTES / 4);

    __shared__ float2 lds2[DD * 65];          // padded [l][r] float2 (stride 65)
    const float2* src2 = (const float2*)base;
    for (int e = threadIdx.x; e < DD * DD; e += 256) {
        const int l = e >> 6, r = e & 63;
        lds2[l * 65 + r] = src2[e];
    }
    __syncthreads();

    uint32_t* out = (uint32_t*)base;          // front 16 KB = 4096 dwords
    for (int id = threadIdx.x; id < 4096; id += 256) {
        const int d = id & 31;                // dword within row (k = 2d, 2d+1)
        const int m = (id >> 5) & 63;
        const int w = id >> 11;
        const int k0 = 2 * d, k1 = 2 * d + 1;
        float a0, a1;
        if (!right) {                         // left: A = W^T
            a0 = ((const float*)&lds2[k0 * 65 + m])[w];
            a1 = ((const float*)&lds2[k1 * 65 + m])[w];
        } else {                              // right: A = W
            a0 = ((const float*)&lds2[m * 65 + k0])[w];
            a1 = ((const float*)&lds2[m * 65 + k1])[w];
        }
        const uint32_t cell = (__float_as_uint(a1) & 0xFFFF0000u)
                            | (__float_as_uint(a0) >> 16);
        out[w * 2048 + m * 32 + ((((unsigned)d >> 2) ^ (m & 7)) << 2) + (d & 3)] = cell;
    }
}

__device__ __forceinline__ void dma16(const void* gp, void* lp) {
    __builtin_amdgcn_global_load_lds(
        (const __attribute__((address_space(1))) uint32_t*)gp,
        (__attribute__((address_space(3))) uint32_t*)lp, 16, 0, 0);
}

__device__ __forceinline__ uint32_t pkbf(float lo, float hi) {
    return (__float_as_uint(hi) & 0xFFFF0000u) | (__float_as_uint(lo) >> 16);
}

// x0*w0 + x1*w1 on a packed bf16 pair (2 ops if v_pk_fma_bf16 exists; correct either way)
__device__ __forceinline__ uint32_t combine2(uint32_t w0, uint32_t w1,
                                             __hip_bfloat162 x0, __hip_bfloat162 x1) {
    __hip_bfloat162 a = __hmul2(x1, *(const __hip_bfloat162*)&w1);
    a = __hfma2(x0, *(const __hip_bfloat162*)&w0, a);
    return *(const uint32_t*)&a;
}

// ---------------------------------------------------------------------------
// Stage 1: per (side, segment, batch) compute the 64x64 bf16 product of the
// segment's 64 site maps via MFMA. 256 blocks x 4 waves; wave = one batch.
// Shared 4-slot DMA ring (prefetch depth 2), raw s_barrier + per-wave
// vmcnt(8) so the DMA queue never drains. Running product T is wave-private
// in LDS (C/D-layout -> B-layout round-trip, swizzled).
// Result P written bf16 col-major [c][r] into the slab BACK halves (free
// 16 KB behind each packed slab).
// ---------------------------------------------------------------------------
__global__ __launch_bounds__(256, 1) void stage1_kernel(
        const float* __restrict__ x, float* __restrict__ wl, float* __restrict__ wr) {
    const int bid  = blockIdx.x;          // 256 blocks
    const int side = bid >> 7;            // 0 left, 1 right
    const int seg  = (bid >> 4) & 7;
    const int bq   = bid & 15;
    const int wave = threadIdx.x >> 6;
    const int lane = threadIdx.x & 63;
    const int b    = bq * 4 + wave;
    const int m5   = lane & 31;
    const int h    = lane >> 5;

    __shared__ __align__(16) char  ring[4][PACK_BYTES];   // 64 KB shared W ring
    __shared__ __align__(16) char  tbuf[4][8192];         // per-wave T (bf16, swizzled col-major)
    __shared__ float2 xs[4][SEGLEN];

    char* wbuf = (char*)(side ? wr : wl);

    // x in chain order for this wave's segment
    {
        const float2* xp = ((const float2*)x) + (size_t)b * 1024 + (side ? NSITE : 0);
        const int t = lane;
        const int s = seg * SEGLEN + (side ? (SEGLEN - 1 - t) : t);
        xs[wave][t] = xp[s];
    }

    // T := identity (bf16, swizzled col-major: byte = c*128 + ((r>>3)^(c&7))*16 + (r&7)*2)
    {
        uint32_t* tb = (uint32_t*)tbuf[wave];
        #pragma unroll
        for (int i0 = 0; i0 < 32; ++i0) {
            const int i = lane + 64 * i0;
            const int c = i >> 5, blkp = (i >> 2) & 7, word = i & 3;
            const int r0 = ((blkp ^ (c & 7)) << 3) + word * 2;
            uint32_t v = 0;
            if (r0 == c)     v |= 0x3F80u;
            if (r0 + 1 == c) v |= 0x3F800000u;
            tb[i] = v;
        }
    }

    // site (chain order t) -> global slab address
    auto siteAddr = [&](int t) -> const char* {
        const int s = seg * SEGLEN + (side ? (SEGLEN - 1 - t) : t);
        return wbuf + (size_t)s * SLAB_BYTES;
    };

    // prime ring slots 0,1 (each wave: 4 of the 16 chunks)
    #pragma unroll
    for (int t0 = 0; t0 < 2; ++t0) {
        const char* sb = siteAddr(t0);
        char* lb = ring[t0];
        #pragma unroll
        for (int c = 0; c < 4; ++c) {
            const int ch = wave * 4 + c;
            dma16(sb + ch * 1024 + lane * 16, lb + ch * 1024);
        }
    }

    f32x16 accQ[2][2] = {};   // last site's T in registers (also mirrored in tbuf)

    for (int t = 0; t < SEGLEN; ++t) {
        // prefetch t+2 (clamped dummy at the tail keeps vmcnt cadence uniform)
        int t2 = t + 2; if (t2 > SEGLEN - 1) t2 = SEGLEN - 1;
        {
            const char* sb = siteAddr(t2);
            char* lb = ring[(t + 2) & 3];
            #pragma unroll
            for (int c = 0; c < 4; ++c) {
                const int ch = wave * 4 + c;
                dma16(sb + ch * 1024 + lane * 16, lb + ch * 1024);
            }
        }
        // own oldest 4 DMAs (slot t) complete; barrier covers the other waves' chunks
        asm volatile("s_waitcnt vmcnt(8)" ::: "memory");
        asm volatile("s_barrier" ::: "memory");

        const uint32_t* wsl = (const uint32_t*)ring[t & 3];
        uint32_t* tb = (uint32_t*)tbuf[wave];

        const float2 xv = xs[wave][t];
        __hip_bfloat162 x0b, x1b;
        x0b.x = __float2bfloat16(xv.x); x0b.y = x0b.x;
        x1b.x = __float2bfloat16(xv.y); x1b.y = x1b.x;

        f32x16 acc[2][2] = {};
        #pragma unroll
        for (int kk = 0; kk < 4; ++kk) {
            const int blk = (((2 * kk + h) ^ (m5 & 7)) << 2);
            // B-frags (running T) from tbuf
            union { bf16x8 v; uint4 u; } bf[2];
            #pragma unroll
            for (int j = 0; j < 2; ++j)
                bf[j].u = *(const uint4*)(tb + j * 1024 + m5 * 32 + blk);
            // A-frags: x-combined W, from the ring
            #pragma unroll
            for (int i = 0; i < 2; ++i) {
                const uint4 w0 = *(const uint4*)(wsl + i * 1024 + m5 * 32 + blk);
                const uint4 w1 = *(const uint4*)(wsl + 2048 + i * 1024 + m5 * 32 + blk);
                union { bf16x8 v; uint32_t u[4]; } a;
                a.u[0] = combine2(w0.x, w1.x, x0b, x1b);
                a.u[1] = combine2(w0.y, w1.y, x0b, x1b);
                a.u[2] = combine2(w0.z, w1.z, x0b, x1b);
                a.u[3] = combine2(w0.w, w1.w, x0b, x1b);
                #pragma unroll
                for (int j = 0; j < 2; ++j)
                    acc[i][j] = __builtin_amdgcn_mfma_f32_32x32x16_bf16(
                        a.v, bf[j].v, acc[i][j], 0, 0, 0);
            }
        }

        // T_new -> tbuf (bf16, swizzled col-major). Reads above already issued;
        // single-wave program order makes the overwrite safe.
        #pragma unroll
        for (int i = 0; i < 2; ++i)
            #pragma unroll
            for (int j = 0; j < 2; ++j) {
                const int cb = j * 32 + m5;
                #pragma unroll
                for (int q = 0; q < 4; ++q) {
                    const uint32_t lo = pkbf(acc[i][j][4 * q + 0], acc[i][j][4 * q + 1]);
                    const uint32_t hi = pkbf(acc[i][j][4 * q + 2], acc[i][j][4 * q + 3]);
                    const int byte = cb * 128 + (((4 * i + q) ^ (m5 & 7)) << 4) + 8 * h;
                    uint2 val; val.x = lo; val.y = hi;
                    *(uint2*)(tbuf[wave] + byte) = val;
                }
            }
        accQ[0][0] = acc[0][0]; accQ[0][1] = acc[0][1];
        accQ[1][0] = acc[1][0]; accQ[1][1] = acc[1][1];
    }

    // write P (= final T) bf16 col-major [c][r] to the slab back-half
    {
        char* pdst = wbuf + (size_t)(b * NSEG + seg) * SLAB_BYTES + PACK_BYTES;
        #pragma unroll
        for (int i = 0; i < 2; ++i)
            #pragma unroll
            for (int j = 0; j < 2; ++j) {
                const int cb = j * 32 + m5;
                #pragma unroll
                for (int q = 0; q < 4; ++q) {
                    const int r0 = i * 32 + q * 8 + h * 4;
                    uint2 val;
                    val.x = pkbf(accQ[i][j][4 * q + 0], accQ[i][j][4 * q + 1]);
                    val.y = pkbf(accQ[i][j][4 * q + 2], accQ[i][j][4 * q + 3]);
                    *(uint2*)(pdst + cb * 128 + r0 * 2) = val;
                }
            }
    }
    asm volatile("s_waitcnt vmcnt(0)" ::: "memory");   // drain DMA before endpgm
}

// ---------------------------------------------------------------------------
// Stage 2: per chain, fold the 8 segment matrices into the boundary vector.
// v <- P_g v; left g = 0..7, right g = 7..0. P stored col-major [c][r] bf16.
// ---------------------------------------------------------------------------
__global__ __launch_bounds__(64) void stage2_kernel(
        const float* __restrict__ wl, const float* __restrict__ wr,
        float* __restrict__ vbuf) {
    const int chain = blockIdx.x;        // 0..127
    const int side  = chain >> 6;
    const int b     = chain & 63;
    const int lane  = threadIdx.x;
    const char* wbuf = (const char*)(side ? wr : wl);

    __shared__ __align__(16) float vsh[DD];
    vsh[lane] = (lane == 0) ? 1.0f : 0.0f;

    for (int gi = 0; gi < NSEG; ++gi) {
        const int g = side ? (NSEG - 1 - gi) : gi;
        const uint16_t* P = (const uint16_t*)(wbuf
            + (size_t)(b * NSEG + g) * SLAB_BYTES + PACK_BYTES);
        float acc = 0.f;
        #pragma unroll 16
        for (int c = 0; c < DD; ++c) {
            const float pv = __uint_as_float(((uint32_t)P[c * 64 + lane]) << 16);
            acc = fmaf(vsh[c], pv, acc);
        }
        vsh[lane] = acc;                 // single-wave program order
    }
    vbuf[chain * DD + lane] = vsh[lane];
}

// out[b,o] = sum_{l,r} vL[b,l] * core[o,l,r] * wR[b,r]
__global__ __launch_bounds__(64) void finalize_kernel(
        const float* __restrict__ core,
        const float* __restrict__ vbuf,
        float* __restrict__ out) {
    const int b    = blockIdx.x;
    const int lane = threadIdx.x;
    __shared__ float vls[DD];
    vls[lane] = vbuf[b * DD + lane];
    const float wr = vbuf[(NB + b) * DD + lane];
    __syncthreads();
    for (int o = 0; o < NO; ++o) {
        float acc = 0.f;
        #pragma unroll 8
        for (int l = 0; l < DD; ++l)
            acc += vls[l] * core[(o * DD + l) * DD + lane];
        acc *= wr;
        #pragma unroll
        for (int off = 32; off > 0; off >>= 1)
            acc += __shfl_xor(acc, off, 64);
        if (lane == 0) out[b * NO + o] = acc;
    }
}

extern "C" void kernel_launch(void* const* d_in, const int* in_sizes, int n_in,
                              void* d_out, int out_size, void* d_ws, size_t ws_size,
                              hipStream_t stream) {
    const float* x    = (const float*)d_in[0];   // [64][1024][2]
    float*       wl   = (float*)d_in[1];         // [512][64][64][2] -> packed + P scratch
    const float* core = (const float*)d_in[2];   // [10][64][64]
    float*       wr   = (float*)d_in[3];         // [512][64][64][2] -> packed + P scratch
    float* vbuf = (float*)d_ws;                  // 32 KB

    pack_kernel<<<2 * NSITE, 256, 0, stream>>>(wl, wr);
    stage1_kernel<<<256, 256, 0, stream>>>(x, wl, wr);
    stage2_kernel<<<2 * NB, 64, 0, stream>>>(wl, wr, vbuf);
    finalize_kernel<<<NB, DD, 0, stream>>>(core, vbuf, (float*)d_out);
}

// Round 4
// 182.142 us; speedup vs baseline: 6.2712x; 1.3140x over previous
//
#include <hip/hip_runtime.h>
#include <stdint.h>

#define NSITE 512
#define DD    64
#define NB    64
#define NO    10
#define NSEG  16
#define SEGLEN 32
#define SLAB_BYTES 32768   // fp32 site slab stride
#define PACK_BYTES 16384   // packed bf16 Wstk image (front half of slab)

typedef short bf16x8 __attribute__((ext_vector_type(8)));
typedef float f32x16 __attribute__((ext_vector_type(16)));

// trunc-pack two f32 -> packed bf16 dword (lo=a, hi=b) in ONE v_perm_b32
__device__ __forceinline__ uint32_t pk2(float a, float b) {
    return __builtin_amdgcn_perm(__float_as_uint(b), __float_as_uint(a), 0x07060302);
}

// ---------------------------------------------------------------------------
// Pack W fp32 [s][l][r][w] -> bf16 K-stacked A-operand image, IN PLACE (front
// 16 KB of each 32 KB slab).  A[m][kap=2k+w] = left: W_w[k][m] (transpose),
// right: W_w[m][k].  Image layout: dword od = chunk*256 + H*128 + m5*4 + d,
// chunk = (m>>5)*8 + (kap>>4), H = (kap>>3)&1, m5 = m&31, d = ((kap&7)>>1);
// dword = {bf(w=0), bf(w=1)} at k = 8*(chunk&7) + 4H + d.  A-frag read in
// stage1 is then *(uint4*)(ring + chunk*1024 + lane*16): lane-contiguous,
// bank-conflict-free, and global_load_lds copies the image verbatim.
// ---------------------------------------------------------------------------
__global__ __launch_bounds__(256) void pack_kernel(float* __restrict__ wl,
                                                   float* __restrict__ wr) {
    const int g = blockIdx.x;                 // 0..1023
    const int right = (g >= NSITE) ? 1 : 0;
    const int s = right ? g - NSITE : g;
    float* base = (right ? wr : wl) + (size_t)s * (SLAB_BYTES / 4);

    __shared__ float2 st[DD * 65];            // padded [l][r] (w0,w1) pairs
    const float2* src2 = (const float2*)base;
    for (int e = threadIdx.x; e < DD * DD; e += 256)
        st[(e >> 6) * 65 + (e & 63)] = src2[e];
    __syncthreads();

    uint32_t* out = (uint32_t*)base;          // front 16 KB = 4096 dwords
    #pragma unroll
    for (int rr = 0; rr < 16; ++rr) {
        const int od = rr * 256 + threadIdx.x;        // coalesced writes
        const int chunk = od >> 8, i = chunk >> 3, sk = chunk & 7;
        const int H = (od >> 7) & 1, m5 = (od >> 2) & 31, d = od & 3;
        const int m = 32 * i + m5, k = 8 * sk + 4 * H + d;
        const float2 a = right ? st[m * 65 + k] : st[k * 65 + m];
        out[od] = pk2(a.x, a.y);              // lo = w0, hi = w1
    }
}

__device__ __forceinline__ void dma16(const void* gp, void* lp) {
    __builtin_amdgcn_global_load_lds(
        (const __attribute__((address_space(1))) uint32_t*)gp,
        (__attribute__((address_space(3))) uint32_t*)lp, 16, 0, 0);
}

// ---------------------------------------------------------------------------
// Stage 1: per (side, segment-of-32, batch) build the 64x64 segment product
// via MFMA with K=128 per site (x-combine folded into the contraction).
// 512 blocks x 4 waves (2 blocks/CU); wave = one batch; 4-slot shared DMA
// ring, prefetch depth 2, vmcnt(8)+s_barrier (round-3-proven cadence).
// T stays ENTIRELY in registers: B-frag for kap-step s = own-lane acc regs
// 4(s&3)..+3 of quadrant [s>>2][cj], scaled {x0,x1} and perm-packed.
// ---------------------------------------------------------------------------
__global__ __launch_bounds__(256, 2) void stage1_kernel(
        const float* __restrict__ x, float* __restrict__ wl, float* __restrict__ wr) {
    const int bid  = blockIdx.x;          // 0..511
    const int side = bid >> 8;
    const int seg  = (bid >> 4) & 15;
    const int bq   = bid & 15;
    const int wave = threadIdx.x >> 6;
    const int lane = threadIdx.x & 63;
    const int b    = bq * 4 + wave;
    const int m5   = lane & 31;
    const int H    = lane >> 5;

    __shared__ __align__(16) char ring[4][PACK_BYTES];   // 64 KB
    __shared__ float2 xs[4][SEGLEN];

    char* wbuf = (char*)(side ? wr : wl);

    if (lane < SEGLEN) {
        const float2* xp = ((const float2*)x) + (size_t)b * 1024 + (side ? NSITE : 0);
        const int sg = seg * SEGLEN + (side ? SEGLEN - 1 - lane : lane);
        xs[wave][lane] = xp[sg];
    }

    auto siteAddr = [&](int t) -> const char* {
        const int sg = seg * SEGLEN + (side ? SEGLEN - 1 - t : t);
        return wbuf + (size_t)sg * SLAB_BYTES;
    };

    #pragma unroll
    for (int t0 = 0; t0 < 2; ++t0) {
        const char* sb = siteAddr(t0);
        #pragma unroll
        for (int c = 0; c < 4; ++c) {
            const int ch = wave * 4 + c;
            dma16(sb + ch * 1024 + lane * 16, ring[t0] + ch * 1024);
        }
    }

    // acc := Identity (C/D layout: row=(q&3)+8(q>>2)+4H, col=32j+m5)
    f32x16 acc[2][2];
    #pragma unroll
    for (int i = 0; i < 2; ++i)
        #pragma unroll
        for (int j = 0; j < 2; ++j)
            #pragma unroll
            for (int q = 0; q < 16; ++q) {
                const int row = (q & 3) + 8 * (q >> 2) + 4 * H;
                acc[i][j][q] = (i == j && row == m5) ? 1.f : 0.f;
            }

    for (int t = 0; t < SEGLEN; ++t) {
        int t2 = t + 2; if (t2 > SEGLEN - 1) t2 = SEGLEN - 1;   // clamped dummy keeps cadence
        {
            const char* sb = siteAddr(t2);
            char* lb = ring[(t + 2) & 3];
            #pragma unroll
            for (int c = 0; c < 4; ++c) {
                const int ch = wave * 4 + c;
                dma16(sb + ch * 1024 + lane * 16, lb + ch * 1024);
            }
        }
        asm volatile("s_waitcnt vmcnt(8)" ::: "memory");
        asm volatile("s_barrier" ::: "memory");

        const char* rb = ring[t & 3];
        uint4 af[2][8];
        #pragma unroll
        for (int i = 0; i < 2; ++i)
            #pragma unroll
            for (int sk = 0; sk < 8; ++sk)
                af[i][sk] = *(const uint4*)(rb + (i * 8 + sk) * 1024 + lane * 16);

        const float2 xv = xs[wave][t];
        f32x16 nacc[2][2] = {};
        #pragma unroll
        for (int sk = 0; sk < 8; ++sk) {
            const int mi = sk >> 2, qb = 4 * (sk & 3);
            union { bf16x8 v; uint32_t u[4]; } bf[2];
            #pragma unroll
            for (int j = 0; j < 2; ++j)
                #pragma unroll
                for (int dlt = 0; dlt < 4; ++dlt) {
                    const float v = acc[mi][j][qb + dlt];
                    bf[j].u[dlt] = pk2(xv.x * v, xv.y * v);   // kap even: x0, odd: x1
                }
            #pragma unroll
            for (int i = 0; i < 2; ++i) {
                union { bf16x8 v; uint4 u; } a; a.u = af[i][sk];
                #pragma unroll
                for (int j = 0; j < 2; ++j)
                    nacc[i][j] = __builtin_amdgcn_mfma_f32_32x32x16_bf16(
                        a.v, bf[j].v, nacc[i][j], 0, 0, 0);
            }
        }
        #pragma unroll
        for (int i = 0; i < 2; ++i)
            #pragma unroll
            for (int j = 0; j < 2; ++j)
                acc[i][j] = nacc[i][j];
    }

    // write P (final T, bf16, uint16 index c*64+r) into slab back-halves
    {
        const int p = b * NSEG + seg;                    // 0..1023 per side
        char* pdst = wbuf + (size_t)(p >> 1) * SLAB_BYTES + PACK_BYTES + (p & 1) * 8192;
        #pragma unroll
        for (int i = 0; i < 2; ++i)
            #pragma unroll
            for (int j = 0; j < 2; ++j) {
                const int c = 32 * j + m5;
                #pragma unroll
                for (int Q = 0; Q < 4; ++Q) {
                    const int r0 = 32 * i + 8 * Q + 4 * H;
                    uint2 val;
                    val.x = pk2(acc[i][j][4 * Q + 0], acc[i][j][4 * Q + 1]);
                    val.y = pk2(acc[i][j][4 * Q + 2], acc[i][j][4 * Q + 3]);
                    *(uint2*)(pdst + c * 128 + r0 * 2) = val;
                }
            }
    }
    asm volatile("s_waitcnt vmcnt(0)" ::: "memory");   // drain DMA before endpgm
}

// ---------------------------------------------------------------------------
// Stage 2: fold 16 segment matrices into the boundary vector per chain.
// 128 blocks x 256 threads; 4 waves split the c-sum, LDS tree reduce.
// ---------------------------------------------------------------------------
__global__ __launch_bounds__(256) void stage2_kernel(
        const float* __restrict__ wl, const float* __restrict__ wr,
        float* __restrict__ vbuf) {
    const int chain = blockIdx.x;        // 0..127
    const int side  = chain >> 6, b = chain & 63;
    const int tid   = threadIdx.x, r = tid & 63, cg = tid >> 6;
    const char* wbuf = (const char*)(side ? wr : wl);

    __shared__ float vsh[DD];
    __shared__ float part[4][DD];
    if (tid < DD) vsh[tid] = (tid == 0) ? 1.f : 0.f;
    __syncthreads();

    for (int gi = 0; gi < NSEG; ++gi) {
        const int g = side ? (NSEG - 1 - gi) : gi;
        const int p = b * NSEG + g;
        const uint16_t* P = (const uint16_t*)(wbuf
            + (size_t)(p >> 1) * SLAB_BYTES + PACK_BYTES + (p & 1) * 8192);
        float acc = 0.f;
        #pragma unroll
        for (int cc = 0; cc < 16; ++cc) {
            const int c = cg * 16 + cc;
            const float pv = __uint_as_float(((uint32_t)P[c * 64 + r]) << 16);
            acc = fmaf(vsh[c], pv, acc);
        }
        part[cg][r] = acc;
        __syncthreads();
        if (tid < DD) vsh[tid] = part[0][tid] + part[1][tid] + part[2][tid] + part[3][tid];
        __syncthreads();
    }
    if (tid < DD) vbuf[chain * DD + tid] = vsh[tid];
}

// out[b,o] = sum_{l,r} vL[b,l] * core[o,l,r] * wR[b,r]
__global__ __launch_bounds__(64) void finalize_kernel(
        const float* __restrict__ core,
        const float* __restrict__ vbuf,
        float* __restrict__ out) {
    const int b    = blockIdx.x;
    const int lane = threadIdx.x;
    __shared__ float vls[DD];
    vls[lane] = vbuf[b * DD + lane];
    const float wr = vbuf[(NB + b) * DD + lane];
    __syncthreads();
    for (int o = 0; o < NO; ++o) {
        float acc = 0.f;
        #pragma unroll 8
        for (int l = 0; l < DD; ++l)
            acc += vls[l] * core[(o * DD + l) * DD + lane];
        acc *= wr;
        #pragma unroll
        for (int off = 32; off > 0; off >>= 1)
            acc += __shfl_xor(acc, off, 64);
        if (lane == 0) out[b * NO + o] = acc;
    }
}

extern "C" void kernel_launch(void* const* d_in, const int* in_sizes, int n_in,
                              void* d_out, int out_size, void* d_ws, size_t ws_size,
                              hipStream_t stream) {
    const float* x    = (const float*)d_in[0];   // [64][1024][2]
    float*       wl   = (float*)d_in[1];         // [512][64][64][2] -> packed + P scratch
    const float* core = (const float*)d_in[2];   // [10][64][64]
    float*       wr   = (float*)d_in[3];         // [512][64][64][2] -> packed + P scratch
    float* vbuf = (float*)d_ws;                  // 32 KB

    pack_kernel<<<2 * NSITE, 256, 0, stream>>>(wl, wr);
    stage1_kernel<<<512, 256, 0, stream>>>(x, wl, wr);
    stage2_kernel<<<2 * NB, 256, 0, stream>>>(wl, wr, vbuf);
    finalize_kernel<<<NB, DD, 0, stream>>>(core, vbuf, (float*)d_out);
}